// Round 4
// baseline (173.802 us; speedup 1.0000x reference)
//
#include <hip/hip_runtime.h>
#include <hip/hip_bf16.h>

#define B_ 128
#define S_ 513
#define H_ 256
#define SH_ (S_ * H_)

typedef __attribute__((ext_vector_type(8))) short short8;
typedef __attribute__((ext_vector_type(4))) float f32x4;

// Pack 8 fp32 -> 8 bf16 (RNE) via the HW packed converter.
static __device__ inline short8 pack8(float4 a, float4 b) {
    union { short8 s; __hip_bfloat162 h[4]; } u;
    u.h[0] = __float22bfloat162_rn(make_float2(a.x, a.y));
    u.h[1] = __float22bfloat162_rn(make_float2(a.z, a.w));
    u.h[2] = __float22bfloat162_rn(make_float2(b.x, b.y));
    u.h[3] = __float22bfloat162_rn(make_float2(b.z, b.w));
    return u.s;
}

// Prep: W fp32 -> bf16 in fragment-major layout (m, kc, d, 8) so the main
// kernel's W fragment loads are coalesced (16 lanes -> 256 B run).
// Also bias sum (256 floats).
__global__ void prep_kernel(const float* __restrict__ W,
                            const float* __restrict__ bias,
                            unsigned short* __restrict__ Wbf,
                            float* __restrict__ bsum) {
    int t = blockIdx.x * 256 + threadIdx.x;
    if (t < 5 * 32 * 256) {                 // one thread per (m, d, kc)
        int m  = t >> 13;                   // t / 8192
        int r  = t & 8191;
        int d  = r >> 5;
        int kc = r & 31;                    // 8-elem k-chunk
        const float* src = W + (((size_t)m * 256 + d) * 256 + kc * 8);
        float4 v0 = *(const float4*)src;
        float4 v1 = *(const float4*)(src + 4);
        *(short8*)(Wbf + ((size_t)(m * 32 + kc) * 256 + d) * 8) = pack8(v0, v1);
    }
    if (t < H_) {
        float s = 0.f;
#pragma unroll
        for (int i = 0; i < 5; ++i) s += bias[i * H_ + t];
        bsum[t] = s;
    }
}

// One WAVE = one self-contained 32(b) x 128(d) x 256(k) GEMM.
// No LDS, no barriers: fragments load directly from global. x fragments are
// 16-row x 64 B gathers served by L2/L3 (x = 67 MB, fits Infinity Cache; the
// 2x d-half re-read is absorbed there). W fragments are fully coalesced from
// the prepped (m, kc, d, 8) layout and L2-hot (640 KB total).
// R0-R3 lesson: barrier-phased kernels sat flat at 44-51 us across all
// occupancy/tile configs -- the cost was phase lockstep + 1-deep load chains,
// so this version removes the phases and gives each K-step 12 independent
// loads with full-unroll scheduling freedom. Output stores are nontemporal
// so the 67 MB write stream does not evict x from L3.
// Budget: acc 64 AGPR + ~55 VGPR < 128 unified -> 4 waves/SIMD (16/CU).
template <int MODE>
__global__ __launch_bounds__(64, 4)
void sel_gemm_kernel(const float* __restrict__ x,
                     const void* __restrict__ Wp,
                     const void* __restrict__ bp,
                     float* __restrict__ out) {
    const int bid = blockIdx.x;
    const int s   = bid >> 3;               // 0..512
    const int r3  = bid & 7;
    const int bg  = (r3 & 3) * 32;          // batch base: 0/32/64/96
    const int dh  = (r3 >> 2) * 128;        // d base: 0/128
    const int m_idx = (s < 3) ? s : ((s & 1) ? 3 : 4);

    const int lane = threadIdx.x & 63;
    const int lrow = lane & 15;
    const int quad = lane >> 4;

    f32x4 acc[2][8];
#pragma unroll
    for (int i = 0; i < 2; ++i)
#pragma unroll
        for (int j = 0; j < 8; ++j) {
            f32x4 z = {0.f, 0.f, 0.f, 0.f};
            acc[i][j] = z;
        }

    const float* xb = x + (size_t)s * H_;

    // ---- K-loop: 8 steps of 32. Fully unrolled; 12 independent loads/step.
#pragma unroll
    for (int kk = 0; kk < 8; ++kk) {
        // x fragments: lane holds x[bg + i*16 + lrow][kk*32 + quad*8 .. +7].
        short8 xfr[2];
#pragma unroll
        for (int i = 0; i < 2; ++i) {
            const float* src =
                xb + (size_t)(bg + i * 16 + lrow) * SH_ + kk * 32 + quad * 8;
            float4 v0 = *(const float4*)src;
            float4 v1 = *(const float4*)(src + 4);
            xfr[i] = pack8(v0, v1);
        }

#pragma unroll
        for (int j = 0; j < 8; ++j) {
            short8 wfr;
            if (MODE == 0) {
                // layout (m, kc, d, 8): d = dh + j*16 + lrow, kc = kk*4+quad
                // -> 16 lanes = 256 B contiguous per quad group.
                const unsigned short* Wk =
                    (const unsigned short*)Wp +
                    ((size_t)(m_idx * 32 + kk * 4 + quad) * 256 +
                     (dh + j * 16 + lrow)) * 8;
                wfr = *(const short8*)Wk;
            } else {
                const float* wrow = (const float*)Wp +
                    (size_t)m_idx * H_ * H_ +
                    (size_t)(dh + j * 16 + lrow) * H_ + kk * 32 + quad * 8;
                float4 v0 = *(const float4*)wrow;
                float4 v1 = *(const float4*)(wrow + 4);
                wfr = pack8(v0, v1);
            }
#pragma unroll
            for (int i = 0; i < 2; ++i)
                acc[i][j] = __builtin_amdgcn_mfma_f32_16x16x32_bf16(
                    wfr, xfr[i], acc[i][j], 0, 0, 0);
        }
    }

    // ---- Epilogue. A=W, B=x -> col(lane&15)=batch, row(quad*4+reg)=d.
    // Per (i,j): one nontemporal float4 store along d. 16 stores/lane.
#pragma unroll
    for (int j = 0; j < 8; ++j) {
        const int d0 = dh + j * 16 + quad * 4;
        f32x4 bj;
        if (MODE == 0) {
            bj = *(const f32x4*)((const float*)bp + d0);
        } else {
            const float* bias = (const float*)bp;
#pragma unroll
            for (int r = 0; r < 4; ++r) {
                float sum = 0.f;
#pragma unroll
                for (int i = 0; i < 5; ++i) sum += bias[i * H_ + d0 + r];
                bj[r] = sum;
            }
        }
#pragma unroll
        for (int i = 0; i < 2; ++i) {
            const int b = bg + i * 16 + lrow;
            f32x4 v = acc[i][j] + bj;
            __builtin_nontemporal_store(
                v, (f32x4*)(out + ((size_t)b * S_ + s) * H_ + d0));
        }
    }
}

extern "C" void kernel_launch(void* const* d_in, const int* in_sizes, int n_in,
                              void* d_out, int out_size, void* d_ws, size_t ws_size,
                              hipStream_t stream) {
    const float* x    = (const float*)d_in[0];
    const float* W    = (const float*)d_in[1];
    const float* bias = (const float*)d_in[2];
    float* out = (float*)d_out;

    const size_t w_elems  = (size_t)5 * H_ * H_;
    const size_t ws_need  = w_elems * sizeof(unsigned short) + H_ * sizeof(float);

    if (ws_size >= ws_need) {
        unsigned short* Wbf = (unsigned short*)d_ws;
        float* bsum = (float*)((char*)d_ws + w_elems * sizeof(unsigned short));
        prep_kernel<<<dim3(160), dim3(256), 0, stream>>>(W, bias, Wbf, bsum);
        sel_gemm_kernel<0><<<dim3(8 * S_), dim3(64), 0, stream>>>(
            x, (const void*)Wbf, (const void*)bsum, out);
    } else {
        sel_gemm_kernel<1><<<dim3(8 * S_), dim3(64), 0, stream>>>(
            x, (const void*)W, (const void*)bias, out);
    }
}

// Round 5
// 128.743 us; speedup vs baseline: 1.3500x; 1.3500x over previous
//
#include <hip/hip_runtime.h>
#include <hip/hip_bf16.h>

#define B_ 128
#define S_ 513
#define H_ 256
#define SH_ (S_ * H_)

typedef __attribute__((ext_vector_type(8))) short short8;
typedef __attribute__((ext_vector_type(4))) float f32x4;

// Pack 8 fp32 -> 8 bf16 (RNE) via the HW packed converter.
static __device__ inline short8 pack8(float4 a, float4 b) {
    union { short8 s; __hip_bfloat162 h[4]; } u;
    u.h[0] = __float22bfloat162_rn(make_float2(a.x, a.y));
    u.h[1] = __float22bfloat162_rn(make_float2(a.z, a.w));
    u.h[2] = __float22bfloat162_rn(make_float2(b.x, b.y));
    u.h[3] = __float22bfloat162_rn(make_float2(b.z, b.w));
    return u.s;
}

// Prep: W fp32 -> bf16 in fragment-major layout (m, kc, d, 8) so the main
// kernel's W fragment loads are coalesced (16 lanes -> 256 B run).
// Also bias sum (256 floats).
__global__ void prep_kernel(const float* __restrict__ W,
                            const float* __restrict__ bias,
                            unsigned short* __restrict__ Wbf,
                            float* __restrict__ bsum) {
    int t = blockIdx.x * 256 + threadIdx.x;
    if (t < 5 * 32 * 256) {                 // one thread per (m, d, kc)
        int m  = t >> 13;                   // t / 8192
        int r  = t & 8191;
        int d  = r >> 5;
        int kc = r & 31;                    // 8-elem k-chunk
        const float* src = W + (((size_t)m * 256 + d) * 256 + kc * 8);
        float4 v0 = *(const float4*)src;
        float4 v1 = *(const float4*)(src + 4);
        *(short8*)(Wbf + ((size_t)(m * 32 + kc) * 256 + d) * 8) = pack8(v0, v1);
    }
    if (t < H_) {
        float s = 0.f;
#pragma unroll
        for (int i = 0; i < 5; ++i) s += bias[i * H_ + t];
        bsum[t] = s;
    }
}

// B-MAJOR decomposition. m(s) is parity for s>=3 (odd->W3, even->W4), so for
// a fixed batch row b, out[b] = x[b] @ W3/W4 by s-parity: two M=255 GEMMs
// over s-rows at stride 2, entirely inside ONE contiguous 525 KB span
// (x[b] and out[b]).  R0-R4 diagnostic: dur == hbm_bytes / ~2.4 TB/s in
// every structural variant -- traffic-bound at an effective-BW ceiling far
// below the 6.3 TB/s streaming ceiling, blamed on the s-major 525-KB-stride
// scatter. This version keeps R1's tile/fragment structure byte-for-byte
// (M=64xN=256xK=256, 4 waves, 32 KB LDS, one barrier) and changes ONLY the
// row->memory mapping: reads are 1 KB runs at 2 KB stride, writes land in
// the same contiguous window.  s in {0,1,2} (W0/W1/W2): 6 edge blocks.
//
// Block map: bid<1024: b = bid>>3, sub = bid&7 -> par = sub&1 (1:odd s, W3;
// 0:even s, W4), tile = sub>>1. Row r (0..63) -> s = sbase + 2r,
// sbase = (par?3:4) + tile*128. Tail tiles have 63 valid rows (rmax=62).
// bid>=1024: edge -> s = e>>1 (0..2), bhalf = e&1; rows are b-rows.
template <int MODE>
__global__ __launch_bounds__(256, 4)
void sel_gemm_kernel(const float* __restrict__ x,
                     const void* __restrict__ Wp,
                     const void* __restrict__ bp,
                     float* __restrict__ out) {
    const int bid = blockIdx.x;
    int m_idx, rmax, rowstride;
    size_t rowbase;
    if (bid < 1024) {
        const int b    = bid >> 3;
        const int sub  = bid & 7;
        const int par  = sub & 1;
        const int tile = sub >> 1;
        const int sbase = (par ? 3 : 4) + tile * 128;
        m_idx     = par ? 3 : 4;
        rowbase   = (size_t)b * S_ + sbase;
        rowstride = 2;
        rmax      = (512 - sbase) >> 1;
        if (rmax > 63) rmax = 63;
    } else {
        const int e  = bid - 1024;          // 0..5
        const int s  = e >> 1;              // 0..2
        const int bh = e & 1;
        m_idx     = s;
        rowbase   = (size_t)bh * 64 * S_ + s;
        rowstride = S_;
        rmax      = 63;
    }

    // 64 rows x 256 bf16 = 32 KB. 16-B chunk c of row r stored at c ^ (r&7):
    // fragment reads land 2 lanes/16B-slot (free); staging writes stay
    // conflict-free (XOR permutes within 128-B stripes).
    __shared__ unsigned short As[64 * 256];

    const int t    = threadIdx.x;
    const int lane = t & 63;
    const int w    = t >> 6;        // 0..3 : d-slice (w*64)
    const int lrow = lane & 15;
    const int quad = lane >> 4;

    // ---- Stage: 64 rows x 256 fp32 -> bf16 LDS, swizzled. 8 chunks/thr.
    // Invalid tail rows clamp to a valid row (loaded, never stored).
#pragma unroll
    for (int i = 0; i < 8; ++i) {
        int flat = i * 256 + t;
        int r = flat >> 5;              // 0..63 (tile row)
        int c = flat & 31;              // 16-B chunk (8 bf16) within row
        int rc = r <= rmax ? r : rmax;
        const float* src = x + (rowbase + (size_t)rowstride * rc) * H_ + c * 8;
        float4 v0 = *(const float4*)src;
        float4 v1 = *(const float4*)(src + 4);
        *(short8*)&As[r * 256 + ((c ^ (r & 7)) * 8)] = pack8(v0, v1);
    }

    f32x4 acc[4][4];
#pragma unroll
    for (int i = 0; i < 4; ++i)
#pragma unroll
        for (int j = 0; j < 4; ++j) {
            f32x4 z = {0.f, 0.f, 0.f, 0.f};
            acc[i][j] = z;
        }

    __syncthreads();   // the only barrier

    // ---- K-loop: 8 steps of 32. W frags from L2 (640 KB total, hot).
#pragma unroll
    for (int kk = 0; kk < 8; ++kk) {
        short8 wfr[4];
        if (MODE == 0) {
            // layout (m, kc, d, 8): lane reads d = w*64 + j*16 + lrow,
            // kc = kk*4 + quad -> 16 lanes = 256 B contiguous.
            const unsigned short* Wk =
                (const unsigned short*)Wp +
                ((size_t)(m_idx * 32 + kk * 4 + quad) * 256) * 8;
#pragma unroll
            for (int j = 0; j < 4; ++j)
                wfr[j] = *(const short8*)(Wk + (size_t)(w * 64 + j * 16 + lrow) * 8);
        } else {
            const float* Wb = (const float*)Wp + (size_t)m_idx * H_ * H_;
#pragma unroll
            for (int j = 0; j < 4; ++j) {
                const float* wrow = Wb + (size_t)(w * 64 + j * 16 + lrow) * H_
                                    + kk * 32 + quad * 8;
                float4 v0 = *(const float4*)wrow;
                float4 v1 = *(const float4*)(wrow + 4);
                wfr[j] = pack8(v0, v1);
            }
        }

        short8 xfr[4];
        const int cc = kk * 4 + quad;   // chunk column of this lane's frag
#pragma unroll
        for (int i = 0; i < 4; ++i) {
            int r = i * 16 + lrow;
            xfr[i] = *(const short8*)&As[r * 256 + ((cc ^ (r & 7)) * 8)];
        }

#pragma unroll
        for (int j = 0; j < 4; ++j)
#pragma unroll
            for (int i = 0; i < 4; ++i)
                acc[i][j] = __builtin_amdgcn_mfma_f32_16x16x32_bf16(
                    wfr[j], xfr[i], acc[i][j], 0, 0, 0);
    }

    // ---- Epilogue. A=W, B=x -> col(lane&15)=tile row, row(quad*4+reg)=d.
    // Per (i,j): one float4 store along d, predicated on row validity.
#pragma unroll
    for (int j = 0; j < 4; ++j) {
        const int d0 = w * 64 + j * 16 + quad * 4;
        f32x4 bj;
        if (MODE == 0) {
            bj = *(const f32x4*)((const float*)bp + d0);
        } else {
            const float* bias = (const float*)bp;
#pragma unroll
            for (int r = 0; r < 4; ++r) {
                float sum = 0.f;
#pragma unroll
                for (int i = 0; i < 5; ++i) sum += bias[i * H_ + d0 + r];
                bj[r] = sum;
            }
        }
#pragma unroll
        for (int i = 0; i < 4; ++i) {
            const int r = i * 16 + lrow;
            if (r <= rmax) {
                f32x4 v = acc[i][j] + bj;
                *(f32x4*)(out + (rowbase + (size_t)rowstride * r) * H_ + d0) = v;
            }
        }
    }
}

extern "C" void kernel_launch(void* const* d_in, const int* in_sizes, int n_in,
                              void* d_out, int out_size, void* d_ws, size_t ws_size,
                              hipStream_t stream) {
    const float* x    = (const float*)d_in[0];
    const float* W    = (const float*)d_in[1];
    const float* bias = (const float*)d_in[2];
    float* out = (float*)d_out;

    const size_t w_elems  = (size_t)5 * H_ * H_;
    const size_t ws_need  = w_elems * sizeof(unsigned short) + H_ * sizeof(float);

    const int grid = 1024 + 6;
    if (ws_size >= ws_need) {
        unsigned short* Wbf = (unsigned short*)d_ws;
        float* bsum = (float*)((char*)d_ws + w_elems * sizeof(unsigned short));
        prep_kernel<<<dim3(160), dim3(256), 0, stream>>>(W, bias, Wbf, bsum);
        sel_gemm_kernel<0><<<dim3(grid), dim3(256), 0, stream>>>(
            x, (const void*)Wbf, (const void*)bsum, out);
    } else {
        sel_gemm_kernel<1><<<dim3(grid), dim3(256), 0, stream>>>(
            x, (const void*)W, (const void*)bias, out);
    }
}